// Round 5
// baseline (3029.927 us; speedup 1.0000x reference)
//
#include <hip/hip_runtime.h>
#include <math.h>

#define B_   128
#define L_   256
#define DW_  100
#define DC_  30
#define HD_  200
#define NT_  18
#define SG   16    // batches per scan block (fills all 16 MFMA N-columns)
#define KP0  160   // padded K for layer-0 GEMM (130 -> 160)
#define KP1  416   // padded K for layer-1 GEMM (400 -> 416)

typedef _Float16 half8 __attribute__((ext_vector_type(8)));
typedef _Float16 half4 __attribute__((ext_vector_type(4)));
typedef float    f32x4 __attribute__((ext_vector_type(4)));

__device__ __forceinline__ float frcp_(float x) { return __builtin_amdgcn_rcpf(x); }
__device__ __forceinline__ float sigm_(float x) { return frcp_(1.0f + __expf(-x)); }
__device__ __forceinline__ float tanh_(float x) { return 1.0f - 2.0f * frcp_(1.0f + __expf(2.0f * x)); }

// barrier that does NOT drain vmcnt: LDS visibility only.
__device__ __forceinline__ void barrier_lgkm() {
    asm volatile("s_waitcnt lgkmcnt(0)" ::: "memory");
    __builtin_amdgcn_s_barrier();
    asm volatile("" ::: "memory");
}

// ---------------- seq_len rank sort -> perm (ascending), one block
__global__ __launch_bounds__(128) void k_sortperm(const int* __restrict__ seq_len,
                                                  int* __restrict__ perm) {
    __shared__ int s[B_];
    int i = threadIdx.x;
    s[i] = seq_len[i];
    __syncthreads();
    int key = s[i], r = 0;
    for (int j = 0; j < B_; j++) {
        int v = s[j];
        r += (v < key) || (v == key && j < i);
    }
    perm[r] = i;
}

// ---------------- embedding gather -> fp16 x (B*L, KP0), pads zeroed
__global__ void k_embed(const int* __restrict__ words, const int* __restrict__ caps,
                        const float* __restrict__ wemb, const float* __restrict__ cemb,
                        _Float16* __restrict__ x) {
    int pos = blockIdx.x;
    int w = words[pos], c = caps[pos];
    _Float16* xp = x + (size_t)pos * KP0;
    for (int t = threadIdx.x; t < KP0; t += blockDim.x) {
        float v = 0.f;
        if (t < DW_) v = wemb[(size_t)w * DW_ + t];
        else if (t < DW_ + DC_) v = cemb[(size_t)c * DC_ + (t - DW_)];
        xp[t] = (_Float16)v;
    }
}

// ---------------- W_ih prep: src (800,K) fp32 -> dst fp16 (1600, Kpad), col = colOff + 4*jh + g
__global__ void k_perm_ih16(const float* __restrict__ src, _Float16* __restrict__ dst,
                            int K, int Kpad, int colOff) {
    int i = blockIdx.x * blockDim.x + threadIdx.x;
    if (i >= 800 * Kpad) return;
    int r = i / Kpad, k = i - r * Kpad;
    int jh = r % 200, g = r / 200;
    int col = colOff + (jh << 2) + g;
    dst[(size_t)col * Kpad + k] = (k < K) ? (_Float16)src[(size_t)r * K + k] : (_Float16)0.f;
}

__global__ void k_bias_perm(const float* bi_f, const float* bh_f,
                            const float* bi_b, const float* bh_b, float* bias) {
    int j = blockIdx.x * blockDim.x + threadIdx.x;
    if (j >= 1600) return;
    int dir = j / 800, r = j - dir * 800;
    int col = dir * 800 + ((r % 200) << 2) + (r / 200);
    bias[col] = dir ? (bi_b[r] + bh_b[r]) : (bi_f[r] + bh_f[r]);
}

__global__ void k_wlog(const float* __restrict__ Wf, const float* __restrict__ bfv,
                       const float* __restrict__ Wb, const float* __restrict__ bbv,
                       float* __restrict__ wlog, float* __restrict__ blog) {
    int i = blockIdx.x * blockDim.x + threadIdx.x;
    if (i < NT_ * 400) {
        int t = i / 400, k = i - t * 400;
        wlog[i] = (k < HD_) ? Wf[t * HD_ + k] : Wb[t * HD_ + (k - HD_)];
    }
    if (i < NT_) blog[i] = bfv[i] + bbv[i];
}

// ---------------- MFMA fp16 GEMM: C(M,1600) = A(M,Kpad) @ Bt(1600,Kpad)^T + bias
__global__ __launch_bounds__(256) void k_gemm16(const _Float16* __restrict__ A,
                                                const _Float16* __restrict__ Bt,
                                                const float* __restrict__ bias,
                                                _Float16* __restrict__ C,
                                                int Kpad) {
    __shared__ __align__(16) _Float16 sA[128 * 40];
    __shared__ __align__(16) _Float16 sB[64 * 40];
    const int tid = threadIdx.x;
    const int w = tid >> 6, l = tid & 63, l15 = l & 15, lq = l >> 4;
    const int m0 = blockIdx.y * 128, n0 = blockIdx.x * 64;
    const int rw = (w >> 1) * 64, cw = (w & 1) * 32;
    f32x4 acc[4][2];
    #pragma unroll
    for (int i = 0; i < 4; i++)
        #pragma unroll
        for (int j = 0; j < 2; j++) acc[i][j] = f32x4{0.f, 0.f, 0.f, 0.f};

    for (int k0 = 0; k0 < Kpad; k0 += 32) {
        {
            int m = tid >> 1, c = (tid & 1) << 4;
            const _Float16* ap = A + (size_t)(m0 + m) * Kpad + k0 + c;
            *(half8*)&sA[m * 40 + c]     = *(const half8*)ap;
            *(half8*)&sA[m * 40 + c + 8] = *(const half8*)(ap + 8);
        }
        {
            int n = tid >> 2, k8 = (tid & 3) << 3;
            *(half8*)&sB[n * 40 + k8] = *(const half8*)&Bt[(size_t)(n0 + n) * Kpad + k0 + k8];
        }
        __syncthreads();
        half8 aF[4], bF[2];
        #pragma unroll
        for (int i = 0; i < 4; i++) aF[i] = *(const half8*)&sA[(rw + i * 16 + l15) * 40 + lq * 8];
        #pragma unroll
        for (int j = 0; j < 2; j++) bF[j] = *(const half8*)&sB[(cw + j * 16 + l15) * 40 + lq * 8];
        #pragma unroll
        for (int i = 0; i < 4; i++)
            #pragma unroll
            for (int j = 0; j < 2; j++)
                acc[i][j] = __builtin_amdgcn_mfma_f32_16x16x32_f16(aF[i], bF[j], acc[i][j], 0, 0, 0);
        __syncthreads();
    }
    #pragma unroll
    for (int j = 0; j < 2; j++) {
        int n = n0 + cw + j * 16 + l15;
        float bv = bias[n];
        #pragma unroll
        for (int i = 0; i < 4; i++) {
            int mrow = m0 + rw + i * 16 + lq * 4;
            #pragma unroll
            for (int r = 0; r < 4; r++)
                C[(size_t)(mrow + r) * 1600 + n] = (_Float16)(acc[i][j][r] + bv);
        }
    }
}

// ---------------- MFMA LSTM scan v11: SG=16 — all 16 MFMA N-columns = 16 batches.
// D-layout (col=lane&15=batch, row=lq*4+reg, cols interleaved 4*jh+g) means each
// lane's C[i] f32x4 IS the (i,f,g,o) gate set of cell (jh = tg_i*4+lq, batch=l15):
// nonlinearity runs fully in-register (no gD LDS hop), h written via ds_write_b16.
// Gate inputs: 7 dwordx2 loads/lane issued at step top; MFMA phase covers latency.
__global__ __launch_bounds__(512) void k_scan11(const _Float16* __restrict__ gates,
                                                const float* __restrict__ Whh_f,
                                                const float* __restrict__ Whh_b,
                                                const int* __restrict__ seq_len,
                                                const int* __restrict__ perm,
                                                _Float16* __restrict__ hout, int ldH) {
    const int dir = blockIdx.x & 1;
    const int b0  = (blockIdx.x >> 1) * SG;
    const int tid = threadIdx.x;
    const int w   = tid >> 6;
    const int l   = tid & 63;
    const int l15 = l & 15;
    const int lq  = l >> 4;

    __shared__ __align__(16) _Float16 hA[2][16 * 232];   // ping-pong h state [p][batch*232+k]
    __shared__ __align__(16) _Float16 bEx[2 * 7 * 512];  // W-frags tiles 48,49 (waves 0,1)
    __shared__ int ssl[SG];
    __shared__ int spb[SG];

    const float* W = dir ? Whh_b : Whh_f;

    // resident W-fragments (A-operand layout): 6 register tiles + tiles 48/49 in LDS
    half8 Breg[6][7];
    #pragma unroll
    for (int i = 0; i < 6; i++) {
        int n  = (w * 6 + i) * 16 + l15;
        int jh = n >> 2, g = n & 3;
        const float* Wr = W + (size_t)(g * 200 + jh) * 200;
        #pragma unroll
        for (int kt = 0; kt < 7; kt++) {
            int k0 = kt * 32 + lq * 8;
            half8 f;
            #pragma unroll
            for (int j = 0; j < 8; j++) {
                int k = k0 + j;
                f[j] = (k < 200) ? (_Float16)Wr[k] : (_Float16)0.f;
            }
            Breg[i][kt] = f;
        }
    }
    if (w < 2) {
        int n  = (48 + w) * 16 + l15;
        int jh = n >> 2, g = n & 3;
        const float* Wr = W + (size_t)(g * 200 + jh) * 200;
        for (int kt = 0; kt < 7; kt++) {
            int k0 = kt * 32 + lq * 8;
            half8 f;
            for (int j = 0; j < 8; j++) {
                int k = k0 + j;
                f[j] = (k < 200) ? (_Float16)Wr[k] : (_Float16)0.f;
            }
            *(half8*)&bEx[(w * 7 + kt) * 512 + l * 8] = f;
        }
    }
    for (int i = tid; i < 2 * 16 * 232; i += 512) (&hA[0][0])[i] = (_Float16)0.f;
    if (tid < SG) {
        int ob = perm[b0 + tid];
        spb[tid] = ob;
        ssl[tid] = seq_len[ob];
    }

    __syncthreads();   // ssl/spb + zeroed hA + bEx visible

    int slmax = 0;
    #pragma unroll
    for (int j = 0; j < SG; j++) slmax = max(slmax, ssl[j]);

    // nonlinearity lane identity: cell (jh = tg_i*4+lq, batch = l15) for each tile i
    const int sl_c = ssl[l15];
    const _Float16* gbase = gates + (size_t)spb[l15] * L_ * 1600 + dir * 800 + 4 * lq;

    // writeback lane identity: lane handles batch m_st, dwords u0+32k (h cols 2u..2u+1)
    const int m_st = tid >> 5;
    const int u0   = tid & 31;
    const int sl_st = ssl[m_st];
    _Float16* hout_b = hout + (size_t)spb[m_st] * L_ * ldH + dir * HD_;

    float cs[7] = {0.f, 0.f, 0.f, 0.f, 0.f, 0.f, 0.f};
    const f32x4 Cz = {0.f, 0.f, 0.f, 0.f};

    for (int t = 0; t < slmax; t++) {
        const int p = t & 1;

        // issue input-gate loads for THIS step; MFMA phase (~1700 cy) covers latency
        half4 gc[7];
        {
            int grow = dir ? ((t < sl_c) ? sl_c - 1 - t : t) : t;
            const _Float16* gR = gbase + (size_t)grow * 1600;
            #pragma unroll
            for (int i = 0; i < 6; i++)
                gc[i] = *(const half4*)(gR + 16 * (w * 6 + i));
            if (w < 2) gc[6] = *(const half4*)(gR + 16 * (48 + w));
        }

        // coalesced writeback of h(t-1) from hA[p] (never drained in-loop)
        if (t > 0) {
            int tp = t - 1;
            bool live = tp < sl_st;
            int row = dir ? (live ? sl_st - 1 - tp : tp) : tp;
            _Float16* ho = hout_b + (size_t)row * ldH;
            #pragma unroll
            for (int k = 0; k < 4; k++) {
                int u = u0 + 32 * k;
                if (u < 100) {
                    unsigned int val = live ? *(const unsigned int*)&hA[p][m_st * 232 + 2 * u] : 0u;
                    *(unsigned int*)(ho + 2 * u) = val;
                }
            }
        }

        // MFMA: D = W @ h(t-1)^T  (A = W-frag, B = h-frag over 16 batches)
        f32x4 C[7];
        #pragma unroll
        for (int i = 0; i < 7; i++) C[i] = Cz;
        #pragma unroll
        for (int kt = 0; kt < 7; kt++) {
            half8 hF = *(const half8*)&hA[p][l15 * 232 + kt * 32 + lq * 8];
            #pragma unroll
            for (int i = 0; i < 6; i++)
                C[i] = __builtin_amdgcn_mfma_f32_16x16x32_f16(Breg[i][kt], hF, C[i], 0, 0, 0);
            if (w < 2) {
                half8 bF = *(const half8*)&bEx[(w * 7 + kt) * 512 + l * 8];
                C[6] = __builtin_amdgcn_mfma_f32_16x16x32_f16(bF, hF, C[6], 0, 0, 0);
            }
        }

        // in-register nonlinearity: C[i] = (i,f,g,o) of cell (tg_i*4+lq, l15)
        #pragma unroll
        for (int i = 0; i < 6; i++) {
            float xi = C[i][0] + (float)gc[i][0];
            float xf = C[i][1] + (float)gc[i][1];
            float xg = C[i][2] + (float)gc[i][2];
            float xo = C[i][3] + (float)gc[i][3];
            float cn = sigm_(xf) * cs[i] + sigm_(xi) * tanh_(xg);
            cs[i] = cn;
            hA[1 - p][l15 * 232 + (w * 6 + i) * 4 + lq] = (_Float16)(sigm_(xo) * tanh_(cn));
        }
        if (w < 2) {
            float xi = C[6][0] + (float)gc[6][0];
            float xf = C[6][1] + (float)gc[6][1];
            float xg = C[6][2] + (float)gc[6][2];
            float xo = C[6][3] + (float)gc[6][3];
            float cn = sigm_(xf) * cs[6] + sigm_(xi) * tanh_(xg);
            cs[6] = cn;
            hA[1 - p][l15 * 232 + (48 + w) * 4 + lq] = (_Float16)(sigm_(xo) * tanh_(cn));
        }

        barrier_lgkm();   // LDS-only drain; vmcnt stays in flight
    }

    // epilogue 1: write back h(slmax-1) from hA[slmax&1]
    {
        int tp = slmax - 1;
        bool live = tp < sl_st;
        int row = dir ? (live ? sl_st - 1 - tp : tp) : tp;
        _Float16* ho = hout_b + (size_t)row * ldH;
        #pragma unroll
        for (int k = 0; k < 4; k++) {
            int u = u0 + 32 * k;
            if (u < 100) {
                unsigned int val = live ? *(const unsigned int*)&hA[slmax & 1][m_st * 232 + 2 * u] : 0u;
                *(unsigned int*)(ho + 2 * u) = val;
            }
        }
    }
    // epilogue 2: zero-fill rows [slmax, L)
    for (int tp = slmax; tp < L_; tp++) {
        _Float16* ho = hout_b + (size_t)tp * ldH;
        #pragma unroll
        for (int k = 0; k < 4; k++) {
            int u = u0 + 32 * k;
            if (u < 100) *(unsigned int*)(ho + 2 * u) = 0u;
        }
    }
}

// ---------------- logits: (B*L,18) = h1(B*L,400 fp16) @ wlog^T + blog
__global__ __launch_bounds__(256) void k_logits(const _Float16* __restrict__ h1,
                                                const float* __restrict__ wlog,
                                                const float* __restrict__ blog,
                                                float* __restrict__ logits) {
    __shared__ float sh[8][400];
    __shared__ float sw[NT_ * 400];
    int p0 = blockIdx.x * 8;
    for (int i = threadIdx.x; i < 8 * 400; i += 256)
        sh[i / 400][i % 400] = (float)h1[(size_t)p0 * 400 + i];
    for (int i = threadIdx.x; i < NT_ * 400; i += 256) sw[i] = wlog[i];
    __syncthreads();
    if (threadIdx.x < 8 * NT_) {
        int pi = threadIdx.x / NT_, tg = threadIdx.x % NT_;
        float a = blog[tg];
        #pragma unroll 4
        for (int k = 0; k < 400; k++) a += sh[pi][k] * sw[tg * 400 + k];
        logits[((size_t)(p0 + pi)) * NT_ + tg] = a;
    }
}

// ---------------- CRF NLL per batch row (54-lane-parallel LSE, single wave)
__global__ __launch_bounds__(64) void k_crf(const float* __restrict__ logits,
                                            const int* __restrict__ target,
                                            const int* __restrict__ seq_len,
                                            const float* __restrict__ trans,
                                            float* __restrict__ out) {
    int b = blockIdx.x, tid = threadIdx.x;
    __shared__ float alpha[NT_];
    int sl = seq_len[b];
    const float* lg = logits + (size_t)b * L_ * NT_;
    const int* tg = target + (size_t)b * L_;

    const bool act = tid < 54;
    const int c = tid / 18, j = tid - c * 18;

    float Tl[6];
    #pragma unroll
    for (int k = 0; k < 6; k++)
        Tl[k] = act ? trans[(6 * c + k) * NT_ + j] : 0.f;

    float gacc = 0.f;
    for (int t = tid; t < L_; t += 64) {
        if (t < sl) {
            gacc += lg[t * NT_ + tg[t]];
            if (t >= 1) gacc += trans[tg[t - 1] * NT_ + tg[t]];
        }
    }
    #pragma unroll
    for (int off = 32; off; off >>= 1) gacc += __shfl_down(gacc, off);
    float gold = __shfl(gacc, 0);

    if (tid < NT_) alpha[tid] = lg[tid];

    const int src1 = (c < 2) ? tid + 18 : tid - 36;
    const int src2 = (c == 0) ? tid + 36 : tid - 18;

    for (int t = 1; t < sl; t++) {
        float m = -1e30f, s = 0.f;
        if (act) {
            float v0 = alpha[6 * c + 0] + Tl[0];
            float v1 = alpha[6 * c + 1] + Tl[1];
            float v2 = alpha[6 * c + 2] + Tl[2];
            float v3 = alpha[6 * c + 3] + Tl[3];
            float v4 = alpha[6 * c + 4] + Tl[4];
            float v5 = alpha[6 * c + 5] + Tl[5];
            m = fmaxf(fmaxf(fmaxf(v0, v1), fmaxf(v2, v3)), fmaxf(v4, v5));
            s = __expf(v0 - m) + __expf(v1 - m) + __expf(v2 - m) +
                __expf(v3 - m) + __expf(v4 - m) + __expf(v5 - m);
        }
        float m1 = __shfl(m, src1), s1 = __shfl(s, src1);
        float m2 = __shfl(m, src2), s2 = __shfl(s, src2);
        if (act && c == 0) {
            float M = fmaxf(m, fmaxf(m1, m2));
            float S = s * __expf(m - M) + s1 * __expf(m1 - M) + s2 * __expf(m2 - M);
            alpha[j] = M + __logf(S) + lg[t * NT_ + j];
        }
    }
    if (tid == 0) {
        float mx = -1e30f;
        for (int i = 0; i < NT_; i++) mx = fmaxf(mx, alpha[i]);
        float s = 0.f;
        for (int i = 0; i < NT_; i++) s += __expf(alpha[i] - mx);
        out[b] = (mx + __logf(s)) - gold;
    }
}

extern "C" void kernel_launch(void* const* d_in, const int* in_sizes, int n_in,
                              void* d_out, int out_size, void* d_ws, size_t ws_size,
                              hipStream_t stream) {
    const int*   words  = (const int*)d_in[0];
    const int*   caps   = (const int*)d_in[1];
    const int*   seq    = (const int*)d_in[2];
    const int*   target = (const int*)d_in[3];
    const float* wemb   = (const float*)d_in[4];
    const float* cemb   = (const float*)d_in[5];
    const float* Wih0f  = (const float*)d_in[6];
    const float* Whh0f  = (const float*)d_in[7];
    const float* bih0f  = (const float*)d_in[8];
    const float* bhh0f  = (const float*)d_in[9];
    const float* Wih0b  = (const float*)d_in[10];
    const float* Whh0b  = (const float*)d_in[11];
    const float* bih0b  = (const float*)d_in[12];
    const float* bhh0b  = (const float*)d_in[13];
    const float* Wih1f  = (const float*)d_in[14];
    const float* Whh1f  = (const float*)d_in[15];
    const float* bih1f  = (const float*)d_in[16];
    const float* bhh1f  = (const float*)d_in[17];
    const float* Wih1b  = (const float*)d_in[18];
    const float* Whh1b  = (const float*)d_in[19];
    const float* bih1b  = (const float*)d_in[20];
    const float* bhh1b  = (const float*)d_in[21];
    const float* Wf     = (const float*)d_in[22];
    const float* bfv    = (const float*)d_in[23];
    const float* Wb     = (const float*)d_in[24];
    const float* bbv    = (const float*)d_in[25];
    const float* trans  = (const float*)d_in[26];

    char* base = (char*)d_ws;
    _Float16* gatesH = (_Float16*)(base + 0);                 // 104,857,600 B (32768x1600)
    _Float16* xbuf   = (_Float16*)(base + 104857600);         // 10,485,760 B (32768x160)
    _Float16* h0b    = (_Float16*)(base + 115343360);         // 27,262,976 B (32768x416)
    _Float16* h1b    = xbuf;  // 26,214,400 B needed; xbuf+h0 region dead by then
    float* logitsb   = (float*)(base + 142606336);            // 2,359,296 B
    _Float16* wihT0  = (_Float16*)(base + 144965632);         // 512,000 B (1600x160)
    _Float16* wihT1  = (_Float16*)(base + 145477632);         // 1,331,200 B (1600x416)
    float* bias0     = (float*)(base + 146808832);            // 6,400 B
    float* bias1     = (float*)(base + 146815232);            // 6,400 B
    float* wlog      = (float*)(base + 146821632);            // 28,800 B
    float* blog      = (float*)(base + 146850432);            // 128 B
    int*   permb     = (int*)(base + 146850560);              // 512 B

    // --- weight prep
    k_perm_ih16<<<(800 * KP0 + 255) / 256, 256, 0, stream>>>(Wih0f, wihT0, 130, KP0, 0);
    k_perm_ih16<<<(800 * KP0 + 255) / 256, 256, 0, stream>>>(Wih0b, wihT0, 130, KP0, 800);
    k_perm_ih16<<<(800 * KP1 + 255) / 256, 256, 0, stream>>>(Wih1f, wihT1, 400, KP1, 0);
    k_perm_ih16<<<(800 * KP1 + 255) / 256, 256, 0, stream>>>(Wih1b, wihT1, 400, KP1, 800);
    k_bias_perm<<<7, 256, 0, stream>>>(bih0f, bhh0f, bih0b, bhh0b, bias0);
    k_bias_perm<<<7, 256, 0, stream>>>(bih1f, bhh1f, bih1b, bhh1b, bias1);
    k_wlog<<<(NT_ * 400 + 255) / 256, 256, 0, stream>>>(Wf, bfv, Wb, bbv, wlog, blog);
    k_sortperm<<<1, 128, 0, stream>>>(seq, permb);

    // --- embeddings (fp16, padded)
    k_embed<<<B_ * L_, 128, 0, stream>>>(words, caps, wemb, cemb, xbuf);

    // zero h0 (its K-pad cols 400..415 must be 0 for the layer-1 GEMM)
    hipMemsetAsync(h0b, 0, (size_t)32768 * KP1 * sizeof(_Float16), stream);

    // --- layer 0
    k_gemm16<<<dim3(25, 256), 256, 0, stream>>>(xbuf, wihT0, bias0, gatesH, KP0);
    k_scan11<<<(B_ / SG) * 2, 512, 0, stream>>>(gatesH, Whh0f, Whh0b, seq, permb, h0b, KP1);

    // --- layer 1
    k_gemm16<<<dim3(25, 256), 256, 0, stream>>>(h0b, wihT1, bias1, gatesH, KP1);
    k_scan11<<<(B_ / SG) * 2, 512, 0, stream>>>(gatesH, Whh1f, Whh1b, seq, permb, h1b, 400);

    // --- logits + CRF
    k_logits<<<(B_ * L_) / 8, 256, 0, stream>>>(h1b, wlog, blog, logitsb);
    k_crf<<<B_, 64, 0, stream>>>(logitsb, target, seq, trans, (float*)d_out);
}